// Round 2
// baseline (1304.183 us; speedup 1.0000x reference)
//
#include <hip/hip_runtime.h>
#include <hip/hip_bf16.h>

#define E_EDGES 1000000

typedef __attribute__((ext_vector_type(8))) short bf16x8;
typedef __attribute__((ext_vector_type(4))) float f32x4;

__device__ __forceinline__ short f2bf(float f) {
    unsigned int x = __float_as_uint(f);
    unsigned int r = (x + 0x7fffu + ((x >> 16) & 1u)) >> 16;
    return (short)r;
}
__device__ __forceinline__ bf16x8 pack8(float4 a, float4 b) {
    bf16x8 r;
    r[0]=f2bf(a.x); r[1]=f2bf(a.y); r[2]=f2bf(a.z); r[3]=f2bf(a.w);
    r[4]=f2bf(b.x); r[5]=f2bf(b.y); r[6]=f2bf(b.z); r[7]=f2bf(b.w);
    return r;
}
__device__ __forceinline__ float silu1(float x) { return x / (1.f + __expf(-x)); }

// ---------------- weight pre-pack: f32 [K][N] -> bf16 MFMA B-fragments ----------
// fragment (nt, ks): 64 lanes x 8 bf16, lane l slot j  <- W[ks*32 + 8*(l>>4)+j][nt*16 + (l&15)]
__global__ void pack_weights_kernel(const float* __restrict__ Wt,
                                    const float* __restrict__ Win,
                                    const float* __restrict__ W1,
                                    const float* __restrict__ W2,
                                    short* __restrict__ ws)
{
    int gid = blockIdx.x * 256 + threadIdx.x;
    const float* src; int K, Nw, local; short* dst;
    if      (gid <  32768) { src = Wt;  K = 128; Nw = 256; local = gid;          dst = ws;         }
    else if (gid <  81920) { src = Win; K = 384; Nw = 128; local = gid -  32768; dst = ws + 32768; }
    else if (gid <  98304) { src = W1;  K = 128; Nw = 128; local = gid -  81920; dst = ws + 81920; }
    else if (gid < 100352) { src = W2;  K = 128; Nw =   4; local = gid -  98304; dst = ws + 98304; }
    else return;
    int KS     = K >> 5;
    int frag   = local >> 9;
    int within = local & 511;
    int l  = within >> 3, j = within & 7;
    int nt = frag / KS,  ks = frag - nt * KS;
    int k  = ks * 32 + ((l >> 4) << 3) + j;
    int n  = nt * 16 + (l & 15);
    float v = (n < Nw) ? src[k * Nw + n] : 0.0f;   // zero-pad W2 cols 4..15
    dst[local] = f2bf(v);
}

// ---------------- fused edge kernel: barrier-free, one wave = 16 edges ---------
__global__ __launch_bounds__(256, 5)
void edge_kernel(const float* __restrict__ h,
                 const float* __restrict__ pos,
                 const float* __restrict__ ea,
                 const float* __restrict__ dst_f,
                 const float* __restrict__ temb,
                 const float* __restrict__ adj,
                 const float* __restrict__ btime,
                 const float* __restrict__ bin,
                 const float* __restrict__ b1,
                 const float* __restrict__ cscale,
                 const int*   __restrict__ ei,
                 const short* __restrict__ ws,
                 float* __restrict__ out)
{
    __shared__ short Tb[4][16 * 136];     // per-wave transpose buffer (4352 B each)
    __shared__ float sCd[4][3][16];
    __shared__ float sAdj[4][3][16];
    __shared__ int   sIr[4][16];

    const int tid = threadIdx.x;
    const int w   = tid >> 6;
    const int l   = tid & 63;
    const int ln  = l & 15;
    const int lg  = l >> 4;
    const int kb  = lg << 3;              // this lane's k-octet base within a 32-k step
    const int e0  = (blockIdx.x * 4 + w) * 16;
    const int em  = e0 + ln;              // this lane's A-row edge

    const int ir = ei[em];
    const int ic = ei[E_EDGES + em];

    // per-edge geometry (quarter-group 0 only), stays in per-wave LDS
    if (lg == 0) {
        sIr[w][ln] = ir;
        float dx = pos[ir*3+0] - pos[ic*3+0];
        float dy = pos[ir*3+1] - pos[ic*3+1];
        float dz = pos[ir*3+2] - pos[ic*3+2];
        float nrm = sqrtf(dx*dx + dy*dy + dz*dz);
        float s = cscale[0] / fmaxf(nrm, 1e-8f);
        sCd[w][0][ln] = dx * s;
        sCd[w][1][ln] = dy * s;
        sCd[w][2][ln] = dz * s;
        sAdj[w][0][ln] = adj[em*3+0];
        sAdj[w][1][ln] = adj[em*3+1];
        sAdj[w][2][ln] = adj[em*3+2];
    }

    const bf16x8* wtP  = reinterpret_cast<const bf16x8*>(ws);          // W_time: 16nt x 4ks
    const bf16x8* winP = reinterpret_cast<const bf16x8*>(ws + 32768);  // W_in:    8nt x 12ks
    const bf16x8* w1P  = reinterpret_cast<const bf16x8*>(ws + 81920);  // W1:      8nt x 4ks
    const bf16x8* w2P  = reinterpret_cast<const bf16x8*>(ws + 98304);  // W2pad:   1nt x 4ks

    // ---- X = h_input @ W_in : A-fragments loaded straight global -> registers ----
    f32x4 accX[8];
    #pragma unroll
    for (int i = 0; i < 8; ++i) accX[i] = (f32x4){0.f,0.f,0.f,0.f};

    #pragma unroll
    for (int seg = 0; seg < 3; ++seg) {
        bf16x8 af[4];
        #pragma unroll
        for (int ks = 0; ks < 4; ++ks) {
            int k0 = (ks << 5) + kb;
            const float* q;
            if (seg == 0)      q = h + (long)ir * 128 + k0;
            else if (seg == 1) q = h + (long)ic * 128 + k0;
            else q = (k0 < 64) ? (ea + (long)em * 64 + k0)
                               : (dst_f + (long)em * 64 + (k0 - 64));
            float4 v0 = *reinterpret_cast<const float4*>(q);
            float4 v1 = *reinterpret_cast<const float4*>(q + 4);
            af[ks] = pack8(v0, v1);
        }
        #pragma unroll
        for (int nt = 0; nt < 8; ++nt)
            #pragma unroll
            for (int ks = 0; ks < 4; ++ks)
                accX[nt] = __builtin_amdgcn_mfma_f32_16x16x32_bf16(
                    af[ks], winP[(nt*12 + (seg<<2) + ks)*64 + l], accX[nt], 0, 0, 0);
    }

    // ---- +b_in, LayerNorm over 128 cols (row lives in a 16-lane quarter-group) ----
    #pragma unroll
    for (int nt = 0; nt < 8; ++nt) {
        float bv = bin[(nt<<4) + ln];
        #pragma unroll
        for (int r = 0; r < 4; ++r) accX[nt][r] += bv;
    }
    #pragma unroll
    for (int r = 0; r < 4; ++r) {
        float p = 0.f, q = 0.f;
        #pragma unroll
        for (int nt = 0; nt < 8; ++nt) { float x = accX[nt][r]; p += x; q += x*x; }
        #pragma unroll
        for (int d2 = 1; d2 < 16; d2 <<= 1) { p += __shfl_xor(p, d2); q += __shfl_xor(q, d2); }
        float mean = p * 0.0078125f;
        float var  = q * 0.0078125f - mean * mean;
        float rstd = rsqrtf(var + 1e-6f);
        #pragma unroll
        for (int nt = 0; nt < 8; ++nt)
            accX[nt][r] = (accX[nt][r] - mean) * rstd;
    }

    // ---- FiLM: T computed nt-sequentially, consumed immediately (no accT[16]) ----
    bf16x8 ttf[4];
    #pragma unroll
    for (int ks = 0; ks < 4; ++ks) {
        const float* q = temb + (long)em * 128 + (ks << 5) + kb;
        float4 v0 = *reinterpret_cast<const float4*>(q);
        float4 v1 = *reinterpret_cast<const float4*>(q + 4);
        v0.x = silu1(v0.x); v0.y = silu1(v0.y); v0.z = silu1(v0.z); v0.w = silu1(v0.w);
        v1.x = silu1(v1.x); v1.y = silu1(v1.y); v1.z = silu1(v1.z); v1.w = silu1(v1.w);
        ttf[ks] = pack8(v0, v1);
    }
    #pragma unroll
    for (int j = 0; j < 8; ++j) {        // scale half: W_time col blocks 8..15
        f32x4 t = (f32x4){0.f,0.f,0.f,0.f};
        #pragma unroll
        for (int ks = 0; ks < 4; ++ks)
            t = __builtin_amdgcn_mfma_f32_16x16x32_bf16(
                ttf[ks], wtP[(((8+j)<<2) + ks)*64 + l], t, 0, 0, 0);
        float bsc = btime[128 + (j<<4) + ln];
        #pragma unroll
        for (int r = 0; r < 4; ++r) accX[j][r] *= (1.f + t[r] + bsc);
    }
    #pragma unroll
    for (int j = 0; j < 8; ++j) {        // shift half: W_time col blocks 0..7
        f32x4 t = (f32x4){0.f,0.f,0.f,0.f};
        #pragma unroll
        for (int ks = 0; ks < 4; ++ks)
            t = __builtin_amdgcn_mfma_f32_16x16x32_bf16(
                ttf[ks], wtP[((j<<2) + ks)*64 + l], t, 0, 0, 0);
        float bsh = btime[(j<<4) + ln];
        #pragma unroll
        for (int r = 0; r < 4; ++r) accX[j][r] += t[r] + bsh;
    }

    // ---- transpose inv (C-layout -> A-layout) through per-wave LDS ----
    short* tb = &Tb[w][0];
    #pragma unroll
    for (int nt = 0; nt < 8; ++nt)
        #pragma unroll
        for (int r = 0; r < 4; ++r)
            tb[((lg<<2) + r)*136 + (nt<<4) + ln] = f2bf(accX[nt][r]);
    bf16x8 iaf[4];
    #pragma unroll
    for (int ks = 0; ks < 4; ++ks)
        iaf[ks] = *reinterpret_cast<const bf16x8*>(&tb[ln*136 + (ks<<5) + kb]);

    // ---- y = silu(inv @ W1 + b1), transpose back through same buffer ----
    f32x4 accY[8];
    #pragma unroll
    for (int i = 0; i < 8; ++i) accY[i] = (f32x4){0.f,0.f,0.f,0.f};
    #pragma unroll
    for (int nt = 0; nt < 8; ++nt)
        #pragma unroll
        for (int ks = 0; ks < 4; ++ks)
            accY[nt] = __builtin_amdgcn_mfma_f32_16x16x32_bf16(
                iaf[ks], w1P[((nt<<2) + ks)*64 + l], accY[nt], 0, 0, 0);
    #pragma unroll
    for (int nt = 0; nt < 8; ++nt) {
        float bv = b1[(nt<<4) + ln];
        #pragma unroll
        for (int r = 0; r < 4; ++r) {
            float x = accY[nt][r] + bv;
            tb[((lg<<2) + r)*136 + (nt<<4) + ln] = f2bf(silu1(x));
        }
    }
    bf16x8 yaf[4];
    #pragma unroll
    for (int ks = 0; ks < 4; ++ks)
        yaf[ks] = *reinterpret_cast<const bf16x8*>(&tb[ln*136 + (ks<<5) + kb]);

    // ---- z = tanh(y @ W2) ; per-edge scalar ; atomic scatter ----
    f32x4 accZ = (f32x4){0.f,0.f,0.f,0.f};
    #pragma unroll
    for (int ks = 0; ks < 4; ++ks)
        accZ = __builtin_amdgcn_mfma_f32_16x16x32_bf16(
            yaf[ks], w2P[ks*64 + l], accZ, 0, 0, 0);
    #pragma unroll
    for (int r = 0; r < 4; ++r) {
        int   m = (lg<<2) + r;            // edge within wave tile
        float z = tanhf(accZ[r]);
        float wt = (ln == 0) ? 1.0f : ((ln < 4) ? sAdj[w][ln-1][m] : 0.0f);
        float v = z * wt;
        v += __shfl_xor(v, 1);
        v += __shfl_xor(v, 2);
        v += __shfl_xor(v, 4);
        v += __shfl_xor(v, 8);
        float s = v * 0.25f;              // mean over 4 heads
        if (ln < 3) {
            atomicAdd(&out[(long)sIr[w][m]*3 + ln], sCd[w][ln][m] * s);
        }
    }
}

extern "C" void kernel_launch(void* const* d_in, const int* in_sizes, int n_in,
                              void* d_out, int out_size, void* d_ws, size_t ws_size,
                              hipStream_t stream) {
    const float* h     = (const float*)d_in[0];
    const float* pos   = (const float*)d_in[1];
    const float* ea    = (const float*)d_in[2];
    const float* dist  = (const float*)d_in[3];
    const float* temb  = (const float*)d_in[4];
    const float* adj   = (const float*)d_in[5];
    const float* Wt    = (const float*)d_in[6];
    const float* bt    = (const float*)d_in[7];
    const float* Win   = (const float*)d_in[8];
    const float* bin   = (const float*)d_in[9];
    const float* W1    = (const float*)d_in[10];
    const float* b1    = (const float*)d_in[11];
    const float* W2    = (const float*)d_in[12];
    const float* cs    = (const float*)d_in[13];
    const int*   ei    = (const int*)d_in[14];
    float*       out   = (float*)d_out;
    short*       ws    = (short*)d_ws;

    pack_weights_kernel<<<(100352 + 255) / 256, 256, 0, stream>>>(Wt, Win, W1, W2, ws);
    hipMemcpyAsync(out, pos, (size_t)out_size * sizeof(float),
                   hipMemcpyDeviceToDevice, stream);
    edge_kernel<<<E_EDGES / 64, 256, 0, stream>>>(h, pos, ea, dist, temb, adj,
                                                  bt, bin, b1, cs, ei, ws, out);
}

// Round 3
// 1023.728 us; speedup vs baseline: 1.2740x; 1.2740x over previous
//
#include <hip/hip_runtime.h>
#include <hip/hip_bf16.h>

#define E_EDGES 1000000

typedef __attribute__((ext_vector_type(8))) short bf16x8;
typedef __attribute__((ext_vector_type(4))) float f32x4;

__device__ __forceinline__ short f2bf(float f) {
    union { __hip_bfloat16 b; short s; } u;
    u.b = __float2bfloat16(f);   // RNE; compiler fuses pairs into v_cvt_pk_bf16_f32
    return u.s;
}
__device__ __forceinline__ bf16x8 pack8(float4 a, float4 b) {
    bf16x8 r;
    r[0]=f2bf(a.x); r[1]=f2bf(a.y); r[2]=f2bf(a.z); r[3]=f2bf(a.w);
    r[4]=f2bf(b.x); r[5]=f2bf(b.y); r[6]=f2bf(b.z); r[7]=f2bf(b.w);
    return r;
}
__device__ __forceinline__ float silu1(float x) { return x / (1.f + __expf(-x)); }
__device__ __forceinline__ float tanh1(float x) {
    float e = __expf(2.f * x);
    return 1.f - 2.f / (e + 1.f);
}

// ---------------- weight pre-pack: f32 [K][N] -> bf16 MFMA B-fragments ----------
// fragment (nt, ks): 64 lanes x 8 bf16, lane l slot j  <- W[ks*32 + 8*(l>>4)+j][nt*16 + (l&15)]
__global__ void pack_weights_kernel(const float* __restrict__ Wt,
                                    const float* __restrict__ Win,
                                    const float* __restrict__ W1,
                                    const float* __restrict__ W2,
                                    short* __restrict__ ws)
{
    int gid = blockIdx.x * 256 + threadIdx.x;
    const float* src; int K, Nw, local; short* dst;
    if      (gid <  32768) { src = Wt;  K = 128; Nw = 256; local = gid;          dst = ws;         }
    else if (gid <  81920) { src = Win; K = 384; Nw = 128; local = gid -  32768; dst = ws + 32768; }
    else if (gid <  98304) { src = W1;  K = 128; Nw = 128; local = gid -  81920; dst = ws + 81920; }
    else if (gid < 100352) { src = W2;  K = 128; Nw =   4; local = gid -  98304; dst = ws + 98304; }
    else return;
    int KS     = K >> 5;
    int frag   = local >> 9;
    int within = local & 511;
    int l  = within >> 3, j = within & 7;
    int nt = frag / KS,  ks = frag - nt * KS;
    int k  = ks * 32 + ((l >> 4) << 3) + j;
    int n  = nt * 16 + (l & 15);
    float v = (n < Nw) ? src[k * Nw + n] : 0.0f;   // zero-pad W2 cols 4..15
    dst[local] = f2bf(v);
}

// ---------------- fused edge kernel: barrier-free, one wave = 16 edges ---------
__global__ __launch_bounds__(256, 4)
void edge_kernel(const float* __restrict__ h,
                 const float* __restrict__ pos,
                 const float* __restrict__ ea,
                 const float* __restrict__ dst_f,
                 const float* __restrict__ temb,
                 const float* __restrict__ adj,
                 const float* __restrict__ btime,
                 const float* __restrict__ bin,
                 const float* __restrict__ b1,
                 const float* __restrict__ cscale,
                 const int*   __restrict__ ei,
                 const short* __restrict__ ws,
                 float* __restrict__ out)
{
    __shared__ short Tb[4][16 * 136];     // per-wave transpose buffer (4352 B each)
    __shared__ float sCd[4][3][16];
    __shared__ float sAdj[4][3][16];
    __shared__ int   sIr[4][16];

    const int tid = threadIdx.x;
    const int w   = tid >> 6;
    const int l   = tid & 63;
    const int ln  = l & 15;
    const int lg  = l >> 4;
    const int kb  = lg << 3;              // this lane's k-octet base within a 32-k step
    const int e0  = (blockIdx.x * 4 + w) * 16;
    const int em  = e0 + ln;              // this lane's A-row edge

    const int ir = ei[em];
    const int ic = ei[E_EDGES + em];

    // per-edge geometry (quarter-group 0 only), stays in per-wave LDS
    if (lg == 0) {
        sIr[w][ln] = ir;
        float dx = pos[ir*3+0] - pos[ic*3+0];
        float dy = pos[ir*3+1] - pos[ic*3+1];
        float dz = pos[ir*3+2] - pos[ic*3+2];
        float nrm = sqrtf(dx*dx + dy*dy + dz*dz);
        float s = cscale[0] / fmaxf(nrm, 1e-8f);
        sCd[w][0][ln] = dx * s;
        sCd[w][1][ln] = dy * s;
        sCd[w][2][ln] = dz * s;
        sAdj[w][0][ln] = adj[em*3+0];
        sAdj[w][1][ln] = adj[em*3+1];
        sAdj[w][2][ln] = adj[em*3+2];
    }

    const bf16x8* wtP  = reinterpret_cast<const bf16x8*>(ws);          // W_time: 16nt x 4ks
    const bf16x8* winP = reinterpret_cast<const bf16x8*>(ws + 32768);  // W_in:    8nt x 12ks
    const bf16x8* w1P  = reinterpret_cast<const bf16x8*>(ws + 81920);  // W1:      8nt x 4ks
    const bf16x8* w2P  = reinterpret_cast<const bf16x8*>(ws + 98304);  // W2pad:   1nt x 4ks

    // ---- X = h_input @ W_in : A-fragments loaded straight global -> registers ----
    f32x4 accX[8];
    #pragma unroll
    for (int i = 0; i < 8; ++i) accX[i] = (f32x4){0.f,0.f,0.f,0.f};

    #pragma unroll
    for (int seg = 0; seg < 3; ++seg) {
        bf16x8 af[4];
        #pragma unroll
        for (int ks = 0; ks < 4; ++ks) {
            int k0 = (ks << 5) + kb;
            const float* q;
            if (seg == 0)      q = h + (long)ir * 128 + k0;
            else if (seg == 1) q = h + (long)ic * 128 + k0;
            else q = (k0 < 64) ? (ea + (long)em * 64 + k0)
                               : (dst_f + (long)em * 64 + (k0 - 64));
            float4 v0 = *reinterpret_cast<const float4*>(q);
            float4 v1 = *reinterpret_cast<const float4*>(q + 4);
            af[ks] = pack8(v0, v1);
        }
        #pragma unroll
        for (int nt = 0; nt < 8; ++nt)
            #pragma unroll
            for (int ks = 0; ks < 4; ++ks)
                accX[nt] = __builtin_amdgcn_mfma_f32_16x16x32_bf16(
                    af[ks], winP[(nt*12 + (seg<<2) + ks)*64 + l], accX[nt], 0, 0, 0);
    }

    // ---- +b_in, LayerNorm over 128 cols (row lives in a 16-lane quarter-group) ----
    #pragma unroll
    for (int nt = 0; nt < 8; ++nt) {
        float bv = bin[(nt<<4) + ln];
        #pragma unroll
        for (int r = 0; r < 4; ++r) accX[nt][r] += bv;
    }
    #pragma unroll
    for (int r = 0; r < 4; ++r) {
        float p = 0.f, q = 0.f;
        #pragma unroll
        for (int nt = 0; nt < 8; ++nt) { float x = accX[nt][r]; p += x; q += x*x; }
        #pragma unroll
        for (int d2 = 1; d2 < 16; d2 <<= 1) { p += __shfl_xor(p, d2); q += __shfl_xor(q, d2); }
        float mean = p * 0.0078125f;
        float var  = q * 0.0078125f - mean * mean;
        float rstd = rsqrtf(var + 1e-6f);
        #pragma unroll
        for (int nt = 0; nt < 8; ++nt)
            accX[nt][r] = (accX[nt][r] - mean) * rstd;
    }

    // ---- FiLM: T computed nt-sequentially, consumed immediately (no accT[16]) ----
    bf16x8 ttf[4];
    #pragma unroll
    for (int ks = 0; ks < 4; ++ks) {
        const float* q = temb + (long)em * 128 + (ks << 5) + kb;
        float4 v0 = *reinterpret_cast<const float4*>(q);
        float4 v1 = *reinterpret_cast<const float4*>(q + 4);
        v0.x = silu1(v0.x); v0.y = silu1(v0.y); v0.z = silu1(v0.z); v0.w = silu1(v0.w);
        v1.x = silu1(v1.x); v1.y = silu1(v1.y); v1.z = silu1(v1.z); v1.w = silu1(v1.w);
        ttf[ks] = pack8(v0, v1);
    }
    #pragma unroll
    for (int j = 0; j < 8; ++j) {        // scale half: W_time col blocks 8..15
        f32x4 t = (f32x4){0.f,0.f,0.f,0.f};
        #pragma unroll
        for (int ks = 0; ks < 4; ++ks)
            t = __builtin_amdgcn_mfma_f32_16x16x32_bf16(
                ttf[ks], wtP[(((8+j)<<2) + ks)*64 + l], t, 0, 0, 0);
        float bsc = btime[128 + (j<<4) + ln];
        #pragma unroll
        for (int r = 0; r < 4; ++r) accX[j][r] *= (1.f + t[r] + bsc);
    }
    #pragma unroll
    for (int j = 0; j < 8; ++j) {        // shift half: W_time col blocks 0..7
        f32x4 t = (f32x4){0.f,0.f,0.f,0.f};
        #pragma unroll
        for (int ks = 0; ks < 4; ++ks)
            t = __builtin_amdgcn_mfma_f32_16x16x32_bf16(
                ttf[ks], wtP[((j<<2) + ks)*64 + l], t, 0, 0, 0);
        float bsh = btime[(j<<4) + ln];
        #pragma unroll
        for (int r = 0; r < 4; ++r) accX[j][r] += t[r] + bsh;
    }

    // ---- transpose inv (C-layout -> A-layout) through per-wave LDS ----
    short* tb = &Tb[w][0];
    #pragma unroll
    for (int nt = 0; nt < 8; ++nt)
        #pragma unroll
        for (int r = 0; r < 4; ++r)
            tb[((lg<<2) + r)*136 + (nt<<4) + ln] = f2bf(accX[nt][r]);
    bf16x8 iaf[4];
    #pragma unroll
    for (int ks = 0; ks < 4; ++ks)
        iaf[ks] = *reinterpret_cast<const bf16x8*>(&tb[ln*136 + (ks<<5) + kb]);

    // ---- y = silu(inv @ W1 + b1), transpose back through same buffer ----
    f32x4 accY[8];
    #pragma unroll
    for (int i = 0; i < 8; ++i) accY[i] = (f32x4){0.f,0.f,0.f,0.f};
    #pragma unroll
    for (int nt = 0; nt < 8; ++nt)
        #pragma unroll
        for (int ks = 0; ks < 4; ++ks)
            accY[nt] = __builtin_amdgcn_mfma_f32_16x16x32_bf16(
                iaf[ks], w1P[((nt<<2) + ks)*64 + l], accY[nt], 0, 0, 0);
    #pragma unroll
    for (int nt = 0; nt < 8; ++nt) {
        float bv = b1[(nt<<4) + ln];
        #pragma unroll
        for (int r = 0; r < 4; ++r) {
            float x = accY[nt][r] + bv;
            tb[((lg<<2) + r)*136 + (nt<<4) + ln] = f2bf(silu1(x));
        }
    }
    bf16x8 yaf[4];
    #pragma unroll
    for (int ks = 0; ks < 4; ++ks)
        yaf[ks] = *reinterpret_cast<const bf16x8*>(&tb[ln*136 + (ks<<5) + kb]);

    // ---- z = tanh(y @ W2) ; per-edge scalar ; atomic scatter ----
    f32x4 accZ = (f32x4){0.f,0.f,0.f,0.f};
    #pragma unroll
    for (int ks = 0; ks < 4; ++ks)
        accZ = __builtin_amdgcn_mfma_f32_16x16x32_bf16(
            yaf[ks], w2P[ks*64 + l], accZ, 0, 0, 0);
    #pragma unroll
    for (int r = 0; r < 4; ++r) {
        int   m = (lg<<2) + r;            // edge within wave tile
        float z = tanh1(accZ[r]);
        float wt = (ln == 0) ? 1.0f : ((ln < 4) ? sAdj[w][ln-1][m] : 0.0f);
        float v = z * wt;
        v += __shfl_xor(v, 1);
        v += __shfl_xor(v, 2);
        v += __shfl_xor(v, 4);
        v += __shfl_xor(v, 8);
        float s = v * 0.25f;              // mean over 4 heads
        if (ln < 3) {
            atomicAdd(&out[(long)sIr[w][m]*3 + ln], sCd[w][ln][m] * s);
        }
    }
}

extern "C" void kernel_launch(void* const* d_in, const int* in_sizes, int n_in,
                              void* d_out, int out_size, void* d_ws, size_t ws_size,
                              hipStream_t stream) {
    const float* h     = (const float*)d_in[0];
    const float* pos   = (const float*)d_in[1];
    const float* ea    = (const float*)d_in[2];
    const float* dist  = (const float*)d_in[3];
    const float* temb  = (const float*)d_in[4];
    const float* adj   = (const float*)d_in[5];
    const float* Wt    = (const float*)d_in[6];
    const float* bt    = (const float*)d_in[7];
    const float* Win   = (const float*)d_in[8];
    const float* bin   = (const float*)d_in[9];
    const float* W1    = (const float*)d_in[10];
    const float* b1    = (const float*)d_in[11];
    const float* W2    = (const float*)d_in[12];
    const float* cs    = (const float*)d_in[13];
    const int*   ei    = (const int*)d_in[14];
    float*       out   = (float*)d_out;
    short*       ws    = (short*)d_ws;

    pack_weights_kernel<<<(100352 + 255) / 256, 256, 0, stream>>>(Wt, Win, W1, W2, ws);
    hipMemcpyAsync(out, pos, (size_t)out_size * sizeof(float),
                   hipMemcpyDeviceToDevice, stream);
    edge_kernel<<<E_EDGES / 64, 256, 0, stream>>>(h, pos, ea, dist, temb, adj,
                                                  bt, bin, b1, cs, ei, ws, out);
}